// Round 1
// baseline (140.873 us; speedup 1.0000x reference)
//
#include <hip/hip_runtime.h>
#include <hip/hip_bf16.h>

typedef __bf16 bf16x8 __attribute__((ext_vector_type(8)));
typedef unsigned short u16x8 __attribute__((ext_vector_type(8)));
typedef float f32x4 __attribute__((ext_vector_type(4)));

#define SLEN 2048
#define DDIM 128
#define NH   32
#define NKVH 8
#define QBLK 64
#define KVB  32
#define DPAD 136   // 128 + 8: row stride 272B -> rows spread across banks, 16B aligned
#define VPAD 40    // 32 + 8:  row stride 80B  -> spread, 16B aligned
#define PPAD 40

static __device__ __forceinline__ unsigned short f2bfu(float f) {
  union { float f; unsigned u; } x; x.f = f;
  return (unsigned short)((x.u + 0x7fffu + ((x.u >> 16) & 1u)) >> 16);
}

static __device__ __forceinline__ f32x4 mfma_bf16(u16x8 a, u16x8 b, f32x4 c) {
  return __builtin_amdgcn_mfma_f32_16x16x32_bf16(
      __builtin_bit_cast(bf16x8, a), __builtin_bit_cast(bf16x8, b), c, 0, 0, 0);
}

__global__ __launch_bounds__(256, 3) void attn_fwd(
    const float* __restrict__ q, const float* __restrict__ k,
    const float* __restrict__ v, const float* __restrict__ sinks,
    const int* __restrict__ bwp, float* __restrict__ out) {
  __shared__ unsigned short Kl[KVB][DPAD];   // K tile, row-major bf16 bits
  __shared__ unsigned short Vt[DDIM][VPAD];  // V tile, transposed: Vt[d][kpos]
  __shared__ unsigned short Pl[4][16][PPAD]; // per-wave P staging

  const int tid  = threadIdx.x;
  const int wid  = tid >> 6;
  const int lane = tid & 63;
  const int ln   = lane & 15;
  const int hi   = lane >> 4;

  const int h   = blockIdx.x >> 5;   // 32 q-tiles per head
  const int qt  = blockIdx.x & 31;
  const int q0  = qt * QBLK;
  const int kvh = h >> 2;            // GQA ratio 4
  const int qrow0 = q0 + wid * 16;   // this wave's 16 q rows

  const int bwv    = bwp[0];
  const int lo_off = (bwv > 0) ? (bwv - 1) : SLEN;  // window start = qpos - lo_off
  const int klo    = max(0, q0 - lo_off);
  const int khi    = q0 + QBLK - 1;

  const float sm_scale = 0.08838834764831845f;  // 1/sqrt(128)

  // ---- Q fragments (A-layout: m = ln, k = hi*8 + j within each 32-chunk) ----
  u16x8 qf[4];
  {
    const float* qp = q + ((h * SLEN + qrow0 + ln) * DDIM) + hi * 8;
    #pragma unroll
    for (int dk = 0; dk < 4; ++dk) {
      float4 f0 = *(const float4*)(qp + dk * 32);
      float4 f1 = *(const float4*)(qp + dk * 32 + 4);
      u16x8 t;
      t[0]=f2bfu(f0.x); t[1]=f2bfu(f0.y); t[2]=f2bfu(f0.z); t[3]=f2bfu(f0.w);
      t[4]=f2bfu(f1.x); t[5]=f2bfu(f1.y); t[6]=f2bfu(f1.z); t[7]=f2bfu(f1.w);
      qf[dk] = t;
    }
  }

  const float sink = sinks[h];
  float m[4], l[4];
  f32x4 oacc[8];
  #pragma unroll
  for (int r = 0; r < 4; ++r) { m[r] = sink; l[r] = 1.0f; }
  #pragma unroll
  for (int nt = 0; nt < 8; ++nt) oacc[nt] = f32x4{0.f, 0.f, 0.f, 0.f};

  const int kb0 = (klo >> 5) << 5;

  // staging assignments
  const int skr = tid >> 3;          // K: row 0..31
  const int skc = (tid & 7) << 4;    // K: col base 0..112
  const int svr = tid & 31;          // V: row 0..31
  const int svc = (tid >> 5) << 4;   // V: col base 0..112

  for (int kb = kb0; kb <= khi; kb += KVB) {
    __syncthreads();  // previous tile fully consumed
    // ---- stage K (row-major) ----
    {
      const float* gk = k + ((kvh * SLEN + kb + skr) * DDIM + skc);
      #pragma unroll
      for (int i = 0; i < 4; ++i) {
        float4 f = *(const float4*)(gk + 4 * i);
        ushort4 p4;
        p4.x = f2bfu(f.x); p4.y = f2bfu(f.y); p4.z = f2bfu(f.z); p4.w = f2bfu(f.w);
        *(ushort4*)&Kl[skr][skc + 4 * i] = p4;
      }
    }
    // ---- stage V (transposed) ----
    {
      const float* gv = v + ((kvh * SLEN + kb + svr) * DDIM + svc);
      #pragma unroll
      for (int i = 0; i < 4; ++i) {
        float4 f = *(const float4*)(gv + 4 * i);
        Vt[svc + 4*i + 0][svr] = f2bfu(f.x);
        Vt[svc + 4*i + 1][svr] = f2bfu(f.y);
        Vt[svc + 4*i + 2][svr] = f2bfu(f.z);
        Vt[svc + 4*i + 3][svr] = f2bfu(f.w);
      }
    }
    __syncthreads();

    // wave-uniform tile skips (barriers above already taken)
    if (kb > qrow0 + 15) continue;                  // entirely above causal diag
    if (kb + KVB - 1 < qrow0 - lo_off) continue;    // entirely before window

    // ---- QK^T: S[16q x 32k] ----
    f32x4 sacc0 = {0,0,0,0}, sacc1 = {0,0,0,0};
    #pragma unroll
    for (int dk = 0; dk < 4; ++dk)
      sacc0 = mfma_bf16(qf[dk], *(const u16x8*)&Kl[ln][dk*32 + hi*8], sacc0);
    #pragma unroll
    for (int dk = 0; dk < 4; ++dk)
      sacc1 = mfma_bf16(qf[dk], *(const u16x8*)&Kl[16 + ln][dk*32 + hi*8], sacc1);

    // ---- online softmax (wave-parallel, per q-row r) ----
    #pragma unroll
    for (int r = 0; r < 4; ++r) {
      const int qpos = qrow0 + hi*4 + r;
      const int kp0 = kb + ln, kp1 = kb + 16 + ln;
      const bool ok0 = (kp0 <= qpos) && (kp0 >= qpos - lo_off);
      const bool ok1 = (kp1 <= qpos) && (kp1 >= qpos - lo_off);
      float v0 = ok0 ? sacc0[r] * sm_scale : -1e30f;
      float v1 = ok1 ? sacc1[r] * sm_scale : -1e30f;
      float mx = fmaxf(v0, v1);
      #pragma unroll
      for (int off = 1; off < 16; off <<= 1)
        mx = fmaxf(mx, __shfl_xor(mx, off));
      const float mn   = fmaxf(m[r], mx);
      const float corr = __expf(m[r] - mn);
      const float p0 = __expf(v0 - mn);   // masked -> exp(-1e30-mn) = 0
      const float p1 = __expf(v1 - mn);
      float ps = p0 + p1;
      #pragma unroll
      for (int off = 1; off < 16; off <<= 1)
        ps += __shfl_xor(ps, off);
      l[r] = l[r] * corr + ps;
      m[r] = mn;
      #pragma unroll
      for (int nt = 0; nt < 8; ++nt) oacc[nt][r] *= corr;
      Pl[wid][hi*4 + r][ln]      = f2bfu(p0);
      Pl[wid][hi*4 + r][16 + ln] = f2bfu(p1);
    }

    // ---- PV: O += P[16x32] * V[32x128] ----
    const u16x8 pa = *(const u16x8*)&Pl[wid][ln][hi*8];
    #pragma unroll
    for (int nt = 0; nt < 8; ++nt) {
      const u16x8 vb = *(const u16x8*)&Vt[nt*16 + ln][hi*8];
      oacc[nt] = mfma_bf16(pa, vb, oacc[nt]);
    }
  }

  // ---- epilogue: out = O / l ----
  #pragma unroll
  for (int r = 0; r < 4; ++r) {
    const float rl = 1.0f / l[r];
    const int qpos = qrow0 + hi*4 + r;
    float* op = out + ((h * SLEN + qpos) * DDIM) + ln;
    #pragma unroll
    for (int nt = 0; nt < 8; ++nt) op[nt * 16] = oacc[nt][r] * rl;
  }
}

extern "C" void kernel_launch(void* const* d_in, const int* in_sizes, int n_in,
                              void* d_out, int out_size, void* d_ws, size_t ws_size,
                              hipStream_t stream) {
  const float* q     = (const float*)d_in[0];
  const float* k     = (const float*)d_in[1];
  const float* v     = (const float*)d_in[2];
  const float* sinks = (const float*)d_in[3];
  const int*   bw    = (const int*)d_in[4];
  float* out = (float*)d_out;
  dim3 grid(NH * (SLEN / QBLK));  // 32 heads * 32 q-tiles = 1024 blocks
  attn_fwd<<<grid, 256, 0, stream>>>(q, k, v, sinks, bw, out);
}

// Round 2
// 125.077 us; speedup vs baseline: 1.1263x; 1.1263x over previous
//
#include <hip/hip_runtime.h>
#include <hip/hip_bf16.h>

typedef __bf16 bf16x8 __attribute__((ext_vector_type(8)));
typedef unsigned short u16x8 __attribute__((ext_vector_type(8)));
typedef float f32x4 __attribute__((ext_vector_type(4)));

#define SLEN 2048
#define DDIM 128
#define NH   32
#define NKVH 8
#define QBLK 64
#define KVB  32
#define KPAD 136   // 32 k-rows x 128d + 8 pad (272B row, 16B aligned)
#define VPAD 40    // 128 d-rows x 32k + 8 pad (80B row, 16B aligned)
#define PPAD 40

static __device__ __forceinline__ unsigned short f2bfu(float f) {
  union { float f; unsigned u; } x; x.f = f;
  return (unsigned short)((x.u + 0x7fffu + ((x.u >> 16) & 1u)) >> 16);
}

static __device__ __forceinline__ f32x4 mfma_bf16(u16x8 a, u16x8 b, f32x4 c) {
  return __builtin_amdgcn_mfma_f32_16x16x32_bf16(
      __builtin_bit_cast(bf16x8, a), __builtin_bit_cast(bf16x8, b), c, 0, 0, 0);
}

// ---- prepass: K fp32 -> bf16 (same layout) ----
__global__ __launch_bounds__(256) void conv_k(const float* __restrict__ src,
                                              unsigned short* __restrict__ dst) {
  const int i = blockIdx.x * 256 + threadIdx.x;   // 262144 threads x 8 floats
  const float4 f0 = ((const float4*)src)[2 * i];
  const float4 f1 = ((const float4*)src)[2 * i + 1];
  u16x8 o;
  o[0] = f2bfu(f0.x); o[1] = f2bfu(f0.y); o[2] = f2bfu(f0.z); o[3] = f2bfu(f0.w);
  o[4] = f2bfu(f1.x); o[5] = f2bfu(f1.y); o[6] = f2bfu(f1.z); o[7] = f2bfu(f1.w);
  ((u16x8*)dst)[i] = o;
}

// ---- prepass: V fp32 [kvh][s][d] -> bf16 transposed [kvh][d][s] ----
__global__ __launch_bounds__(256) void conv_vt(const float* __restrict__ v,
                                               unsigned short* __restrict__ vt) {
  __shared__ unsigned short T[32][34];  // T[s_local][d_local], padded
  const int b   = blockIdx.x;           // kvh*256 + st*4 + dt
  const int dt  = b & 3;
  const int st  = (b >> 2) & 63;
  const int kvh = b >> 8;
  const int r  = threadIdx.x >> 3;      // 0..31 (s_local)
  const int cg = threadIdx.x & 7;       // 0..7  (d chunk of 4)
  const float4 f = *(const float4*)(v + ((size_t)(kvh * SLEN + st * 32 + r) * DDIM) + dt * 32 + cg * 4);
  T[r][cg * 4 + 0] = f2bfu(f.x);
  T[r][cg * 4 + 1] = f2bfu(f.y);
  T[r][cg * 4 + 2] = f2bfu(f.z);
  T[r][cg * 4 + 3] = f2bfu(f.w);
  __syncthreads();
  const int dr = threadIdx.x >> 3;      // 0..31 (d_local)
  ushort4 o;
  o.x = T[cg * 4 + 0][dr];
  o.y = T[cg * 4 + 1][dr];
  o.z = T[cg * 4 + 2][dr];
  o.w = T[cg * 4 + 3][dr];
  *(ushort4*)(vt + (size_t)kvh * DDIM * SLEN + (size_t)(dt * 32 + dr) * SLEN + st * 32 + cg * 4) = o;
}

__global__ __launch_bounds__(256, 3) void attn_fwd(
    const float* __restrict__ q, const unsigned short* __restrict__ kbf,
    const unsigned short* __restrict__ vtg, const float* __restrict__ sinks,
    const int* __restrict__ bwp, float* __restrict__ out) {
  __shared__ unsigned short Kl[KVB][KPAD];    // K tile row-major bf16
  __shared__ unsigned short Vt[DDIM][VPAD];   // V tile transposed Vt[d][kloc]
  __shared__ unsigned short Pl[4][16][PPAD];  // per-wave P staging

  const int tid  = threadIdx.x;
  const int wid  = tid >> 6;
  const int lane = tid & 63;
  const int ln   = lane & 15;
  const int hi   = lane >> 4;

  const int h   = blockIdx.x >> 5;
  const int qt  = blockIdx.x & 31;
  const int q0  = qt * QBLK;
  const int kvh = h >> 2;            // GQA ratio 4
  const int qrow0 = q0 + wid * 16;

  const int bwv    = bwp[0];
  const int lo_off = (bwv > 0) ? (bwv - 1) : SLEN;
  const int klo    = max(0, q0 - lo_off);
  const int khi    = q0 + QBLK - 1;

  const float sm_scale = 0.08838834764831845f;  // 1/sqrt(128)

  // ---- Q fragments (fp32 -> bf16, once per block: cheap) ----
  u16x8 qf[4];
  {
    const float* qp = q + ((size_t)(h * SLEN + qrow0 + ln) * DDIM) + hi * 8;
    #pragma unroll
    for (int dk = 0; dk < 4; ++dk) {
      float4 f0 = *(const float4*)(qp + dk * 32);
      float4 f1 = *(const float4*)(qp + dk * 32 + 4);
      u16x8 t;
      t[0]=f2bfu(f0.x); t[1]=f2bfu(f0.y); t[2]=f2bfu(f0.z); t[3]=f2bfu(f0.w);
      t[4]=f2bfu(f1.x); t[5]=f2bfu(f1.y); t[6]=f2bfu(f1.z); t[7]=f2bfu(f1.w);
      qf[dk] = t;
    }
  }

  const float sink = sinks[h];
  float m[4], l[4];
  f32x4 oacc[8];
  #pragma unroll
  for (int r = 0; r < 4; ++r) { m[r] = sink; l[r] = 1.0f; }
  #pragma unroll
  for (int nt = 0; nt < 8; ++nt) oacc[nt] = f32x4{0.f, 0.f, 0.f, 0.f};

  const int kb0 = (klo >> 5) << 5;
  const unsigned short* Kg = kbf + (size_t)kvh * SLEN * DDIM;
  const unsigned short* Vg = vtg + (size_t)kvh * DDIM * SLEN;

  for (int kb = kb0; kb <= khi; kb += KVB) {
    __syncthreads();  // previous tile fully consumed
    // ---- stage K: 32x128 bf16 = 512 chunks of 16B ----
    #pragma unroll
    for (int c = 0; c < 2; ++c) {
      const int f  = c * 256 + tid;
      const int kr = f >> 4;            // 0..31
      const int kc = (f & 15) * 8;      // u16 col
      *(u16x8*)&Kl[kr][kc] = *(const u16x8*)(Kg + (size_t)(kb + kr) * DDIM + kc);
      const int vr = f >> 2;            // 0..127 (d)
      const int vc = (f & 3) * 8;       // u16 col (k-local)
      *(u16x8*)&Vt[vr][vc] = *(const u16x8*)(Vg + (size_t)vr * SLEN + kb + vc);
    }
    __syncthreads();

    if (kb > qrow0 + 15) continue;                  // above causal diag
    if (kb + KVB - 1 < qrow0 - lo_off) continue;    // before window

    // ---- QK^T: S[16q x 32k] ----
    f32x4 sacc0 = {0,0,0,0}, sacc1 = {0,0,0,0};
    #pragma unroll
    for (int dk = 0; dk < 4; ++dk)
      sacc0 = mfma_bf16(qf[dk], *(const u16x8*)&Kl[ln][dk*32 + hi*8], sacc0);
    #pragma unroll
    for (int dk = 0; dk < 4; ++dk)
      sacc1 = mfma_bf16(qf[dk], *(const u16x8*)&Kl[16 + ln][dk*32 + hi*8], sacc1);

    // ---- online softmax with defer-max (T13, THR=8) ----
    float vv0[4], vv1[4], mx[4];
    bool need = false;
    #pragma unroll
    for (int r = 0; r < 4; ++r) {
      const int qpos = qrow0 + hi*4 + r;
      const int kp0 = kb + ln, kp1 = kb + 16 + ln;
      const bool ok0 = (kp0 <= qpos) && (kp0 >= qpos - lo_off);
      const bool ok1 = (kp1 <= qpos) && (kp1 >= qpos - lo_off);
      vv0[r] = ok0 ? sacc0[r] * sm_scale : -1e30f;
      vv1[r] = ok1 ? sacc1[r] * sm_scale : -1e30f;
      float t = fmaxf(vv0[r], vv1[r]);
      #pragma unroll
      for (int off = 1; off < 16; off <<= 1)
        t = fmaxf(t, __shfl_xor(t, off));
      mx[r] = t;
      need = need || (t > m[r] + 8.0f);
    }
    if (__any(need)) {   // wave-uniform rescale
      #pragma unroll
      for (int r = 0; r < 4; ++r) {
        const float mn   = fmaxf(m[r], mx[r]);
        const float corr = __expf(m[r] - mn);
        l[r] *= corr;
        m[r] = mn;
        #pragma unroll
        for (int nt = 0; nt < 8; ++nt) oacc[nt][r] *= corr;
      }
    }
    #pragma unroll
    for (int r = 0; r < 4; ++r) {
      const float p0 = __expf(vv0[r] - m[r]);   // masked -> 0
      const float p1 = __expf(vv1[r] - m[r]);
      float ps = p0 + p1;
      #pragma unroll
      for (int off = 1; off < 16; off <<= 1)
        ps += __shfl_xor(ps, off);
      l[r] += ps;
      Pl[wid][hi*4 + r][ln]      = f2bfu(p0);
      Pl[wid][hi*4 + r][16 + ln] = f2bfu(p1);
    }

    // ---- PV: O += P[16x32] * V[32x128] ----
    const u16x8 pa = *(const u16x8*)&Pl[wid][ln][hi*8];
    #pragma unroll
    for (int nt = 0; nt < 8; ++nt) {
      const u16x8 vb = *(const u16x8*)&Vt[nt*16 + ln][hi*8];
      oacc[nt] = mfma_bf16(pa, vb, oacc[nt]);
    }
  }

  // ---- epilogue: out = O / l ----
  #pragma unroll
  for (int r = 0; r < 4; ++r) {
    const float rl = 1.0f / l[r];
    const int qpos = qrow0 + hi*4 + r;
    float* op = out + ((size_t)(h * SLEN + qpos) * DDIM) + ln;
    #pragma unroll
    for (int nt = 0; nt < 8; ++nt) op[nt * 16] = oacc[nt][r] * rl;
  }
}

extern "C" void kernel_launch(void* const* d_in, const int* in_sizes, int n_in,
                              void* d_out, int out_size, void* d_ws, size_t ws_size,
                              hipStream_t stream) {
  const float* q     = (const float*)d_in[0];
  const float* k     = (const float*)d_in[1];
  const float* v     = (const float*)d_in[2];
  const float* sinks = (const float*)d_in[3];
  const int*   bw    = (const int*)d_in[4];
  float* out = (float*)d_out;

  unsigned short* kbf = (unsigned short*)d_ws;                 // 8.39 MB
  unsigned short* vtg = kbf + (size_t)NKVH * SLEN * DDIM;      // 8.39 MB

  conv_k <<<dim3((NKVH*SLEN*DDIM) / (256*8)), 256, 0, stream>>>(k, kbf);
  conv_vt<<<dim3(NKVH * 64 * 4),              256, 0, stream>>>(v, vtg);
  attn_fwd<<<dim3(NH * (SLEN / QBLK)),        256, 0, stream>>>(q, kbf, vtg, sinks, bw, out);
}